// Round 10
// baseline (3824.155 us; speedup 1.0000x reference)
//
#include <hip/hip_runtime.h>

typedef _Float16 v8h __attribute__((ext_vector_type(8)));
typedef float    v4f __attribute__((ext_vector_type(4)));

#define MFMA16(A,B,C) __builtin_amdgcn_mfma_f32_16x16x32_f16((A),(B),(C),0,0,0)

#define RPB 4
#define TT  256
#define HH  64
#define KST 144      // f16 stride per A row (72 words ≡ 8 mod 32: 2-way-max frag conflicts)
#define SG  256.0f   // sigmoid index scale (table step 1/256)
#define TG  512.0f   // g-gate tanh index scale (tanh(z)=2*sigma(2z)-1)
#define NLUT 6144    // z in [-12,12], step 1/256
#define IOFF 3072.5f // index center + 0.5 NN rounding offset
#define TSC2 -2.88539008f // -2*log2(e): tanh(c)=2*rcp(1+exp2(c*TSC2))-1

// 1024 blocks x 256 thr = 4 independent blocks/CU (4 waves/SIMD, independent
// barriers -> real latency overlap; the knob R2/R4 could never exploit).
// RPB=4: A rows = h[l15&3] (all 16 C rows alias batch rows 0-3). Lane q
// owns layer (q<2 ? 0 : 1), rows mr..mr+1 (mr=(q&1)*2) -> 2 pointwise
// instances/lane, no idle lanes, 1 barrier/step. MFMA 2x-redundant (pipe
// was 28% loaded). NN sigma LUT (6144, step 1/256) for gates; c-tanh via
// exp2+rcp. VGPR<=128 forced for 16 waves/CU.
__global__ __launch_bounds__(256, 4)
void lstm2_kernel(const float* __restrict__ x,     // [4096][256]
                  const float* __restrict__ Wih0,  // [256][1]
                  const float* __restrict__ Whh0,  // [256][64]
                  const float* __restrict__ bih0,
                  const float* __restrict__ bhh0,
                  const float* __restrict__ Wih1,  // [256][64]
                  const float* __restrict__ Whh1,  // [256][64]
                  const float* __restrict__ bih1,
                  const float* __restrict__ bhh1,
                  const float* __restrict__ Wlin,  // [64][64]
                  const float* __restrict__ blin,
                  float* __restrict__ out)         // [4096][64]
{
    __shared__ float xl[TT][RPB];                      // 4 KB
    __shared__ __align__(16) _Float16 hs[2][RPB][KST]; // 2.25 KB
    __shared__ float hbF[RPB][HH];                     // 1 KB
    __shared__ float lut[NLUT];                        // 24 KB sigma table

    const int tid  = threadIdx.x;
    const int w    = tid >> 6;
    const int l15  = tid & 15;
    const int l3   = tid & 3;          // A-frag row (C row = batch row mod 4)
    const int q    = (tid & 63) >> 4;
    const int row0 = (int)blockIdx.x * RPB;
    const int jj   = w * 16 + l15;
    const bool isA = (q < 2);          // q<2: layer-0 lanes; q>=2: layer-1 lanes
    const int  mr  = (q & 1) * 2;      // my rows: mr, mr+1

    for (int idx = tid; idx < RPB * TT; idx += 256) {
        int m = idx & 3, t = idx >> 2;
        xl[t][m] = x[(row0 + m) * TT + t];
    }
    for (int idx = tid; idx < 2 * RPB * KST; idx += 256)
        ((_Float16*)hs)[idx] = (_Float16)0.f;
    for (int i = tid; i < NLUT; i += 256)
        lut[i] = 1.0f / (1.0f + __expf(-(i - NLUT / 2) * (1.0f / 256.0f)));

    // sigma via nearest-neighbor LUT; f is a pre-scaled index (z*256+IOFF)
    auto lutv = [&](float f) -> float {
        f = __builtin_amdgcn_fmed3f(f, 0.0f, (float)(NLUT - 1));
        return lut[(int)f];
    };
    // tanh(c) via hardware exp2+rcp (near-exact, no gather)
    auto tanhf_fast = [&](float c) -> float {
        return fmaf(2.f, __builtin_amdgcn_rcpf(1.f + __builtin_exp2f(c * TSC2)), -1.f);
    };

    // ---- register-stationary weights, prescaled into index space ----
    float wi0s[4], b0s[4];
    v4f   b1v[4];
    v8h wh0[4][2], wi1[4][2], wh1[4][2];
    #pragma unroll
    for (int tau = 0; tau < 4; tau++) {
        float sc = (tau == 2) ? TG : SG;
        int n = tau * 64 + jj;
        wi0s[tau] = Wih0[n] * sc;
        b0s[tau]  = (bih0[n] + bhh0[n]) * sc + IOFF;
        float b1  = (bih1[n] + bhh1[n]) * sc + IOFF;
        b1v[tau]  = (v4f){b1, b1, b1, b1};
        #pragma unroll
        for (int kk = 0; kk < 2; kk++) {
            int k0 = kk * 32 + q * 8;   // B-frag: B[k0..k0+7][n=lane&15]
            v8h a, b, c;
            #pragma unroll
            for (int j = 0; j < 8; j++) {
                a[j] = (_Float16)(Whh0[n * HH + k0 + j] * sc);
                b[j] = (_Float16)(Wih1[n * HH + k0 + j] * sc);
                c[j] = (_Float16)(Whh1[n * HH + k0 + j] * sc);
            }
            wh0[tau][kk] = a; wi1[tau][kk] = b; wh1[tau][kk] = c;
        }
    }

    float cs[2] = {0.f, 0.f};   // c-state of MY layer, rows mr..mr+1
    __syncthreads();

    // ---- prologue t=0: ha(0) from x(0) only (layer-0 lanes) ----
    if (isA) {
        #pragma unroll
        for (int s = 0; s < 2; s++) {
            int m = mr + s;
            float xv = xl[0][m];
            float iv = lutv(fmaf(xv, wi0s[0], b0s[0]));
            float gv = fmaf(2.f, lutv(fmaf(xv, wi0s[2], b0s[2])), -1.f);
            float ov = lutv(fmaf(xv, wi0s[3], b0s[3]));
            cs[s] = iv * gv;
            hs[0][m][jj] = (_Float16)(ov * tanhf_fast(cs[s]));
        }
    }
    __syncthreads();

    // step k: reads buf[p] {ha(k-1), hb(k-2)}, writes buf[pw] {ha(k), hb(k-1)}
    auto step = [&](int k, int p, int pw, bool last) {
        v8h a0 = *(const v8h*)&hs[p][l3][q * 8];          // ha k 0-31
        v8h a1 = *(const v8h*)&hs[p][l3][32 + q * 8];     // ha k 32-63
        v8h b0 = *(const v8h*)&hs[p][l3][64 + q * 8];     // hb k 0-31
        v8h b1 = *(const v8h*)&hs[p][l3][96 + q * 8];     // hb k 32-63
        int kx = (k < TT) ? k : (TT - 1);                 // k=256: junk x, unused
        float xv0 = xl[kx][mr], xv1 = xl[kx][mr + 1];

        v4f acc0[4], acc1[4];
        #pragma unroll
        for (int tau = 0; tau < 4; tau++) {
            float f0 = fmaf(xv0, wi0s[tau], b0s[tau]);
            float f1 = fmaf(xv1, wi0s[tau], b0s[tau]);
            acc0[tau] = (v4f){f0, f1, f0, f1};            // slots mr,mr+1 correct for either mr
            acc1[tau] = MFMA16(a0, wi1[tau][0], b1v[tau]); // bias as C operand
        }
        #pragma unroll
        for (int tau = 0; tau < 4; tau++) {
            acc0[tau] = MFMA16(a0, wh0[tau][0], acc0[tau]);
            acc0[tau] = MFMA16(a1, wh0[tau][1], acc0[tau]);
            acc1[tau] = MFMA16(a1, wi1[tau][1], acc1[tau]);
            acc1[tau] = MFMA16(b0, wh1[tau][0], acc1[tau]);
            acc1[tau] = MFMA16(b1, wh1[tau][1], acc1[tau]);
        }

        // my gates: q<2 -> layer0 (acc0); q>=2 -> layer1 (acc1); rows mr..mr+1
        v4f g0 = isA ? acc0[0] : acc1[0];
        v4f g1 = isA ? acc0[1] : acc1[1];
        v4f g2 = isA ? acc0[2] : acc1[2];
        v4f g3 = isA ? acc0[3] : acc1[3];

        // stage 1: all 8 sigma gathers issued together (one latency round)
        float sv0[2], sv1[2], sv2[2], sv3[2];
        #pragma unroll
        for (int s = 0; s < 2; s++) {
            sv0[s] = lutv(g0[mr + s]);
            sv1[s] = lutv(g1[mr + s]);
            sv2[s] = lutv(g2[mr + s]);
            sv3[s] = lutv(g3[mr + s]);
        }

        _Float16* wp = &hs[pw][mr][isA ? jj : (64 + jj)];

        // stage 2: c update, trans tanh, h write
        #pragma unroll
        for (int s = 0; s < 2; s++) {
            float iv = sv0[s];
            float fv = sv1[s];
            float gv = fmaf(2.f, sv2[s], -1.f);
            float ov = sv3[s];
            cs[s] = fmaf(fv, cs[s], iv * gv);
            float hv = ov * tanhf_fast(cs[s]);
            wp[s * KST] = (_Float16)hv;
            if (last && !isA) hbF[mr + s][jj] = hv;
        }
        __syncthreads();
    };

    // k = 1..256 (k=256 = layer-1-only epilogue; its ha output junk-but-finite)
    for (int k = 1; k <= TT; k += 2) {
        step(k,     0, 1, false);
        step(k + 1, 1, 0, (k + 1) == TT);
    }

    // ---- out[m][n] = hbF[m][:] . Wlin[n][:] + blin[n] ----
    int m = tid >> 6;            // 0..3
    int n = tid & 63;
    float accO = blin[n];
    #pragma unroll 8
    for (int j = 0; j < HH; j++)
        accO = fmaf(hbF[m][j], Wlin[n * HH + j], accO);
    out[(row0 + m) * HH + n] = accO;
}

extern "C" void kernel_launch(void* const* d_in, const int* in_sizes, int n_in,
                              void* d_out, int out_size, void* d_ws, size_t ws_size,
                              hipStream_t stream) {
    const float* x    = (const float*)d_in[0];
    const float* Wih0 = (const float*)d_in[1];
    const float* Whh0 = (const float*)d_in[2];
    const float* bih0 = (const float*)d_in[3];
    const float* bhh0 = (const float*)d_in[4];
    const float* Wih1 = (const float*)d_in[5];
    const float* Whh1 = (const float*)d_in[6];
    const float* bih1 = (const float*)d_in[7];
    const float* bhh1 = (const float*)d_in[8];
    const float* Wlin = (const float*)d_in[9];
    const float* blin = (const float*)d_in[10];
    // 4096 rows / 4 per block = 1024 blocks = 4 independent blocks/CU
    lstm2_kernel<<<1024, 256, 0, stream>>>(x, Wih0, Whh0, bih0, bhh0,
                                           Wih1, Whh1, bih1, bhh1,
                                           Wlin, blin, (float*)d_out);
}

// Round 12
// 370.539 us; speedup vs baseline: 10.3205x; 10.3205x over previous
//
#include <hip/hip_runtime.h>

typedef _Float16 v8h __attribute__((ext_vector_type(8)));
typedef float    v4f __attribute__((ext_vector_type(4)));

#define MFMA16(A,B,C) __builtin_amdgcn_mfma_f32_16x16x32_f16((A),(B),(C),0,0,0)

#define RPB 8
#define TT  256
#define HH  64
#define KST 136      // f16 stride per A row: k 0-63 = ha, 64-127 = hb, 8 pad
#define SG  256.0f   // sigmoid index scale (table step 1/256)
#define TG  512.0f   // g-gate tanh index scale (tanh(z)=2*sigma(2z)-1)
#define IOFF 4096.5f // index center + 0.5 NN rounding offset
#define TSC2 -2.88539008f    // -2*log2(e): tanh(c)=2*rcp(1+exp2(c*TSC2))-1
#define YK   -0.0056355275f  // -log2(e)/256: index-space -> exp2 arg
#define YB   23.0859385f     // IOFF*log2(e)/256 for IOFF=4096.5 (R11 bug: had 3072.5's value)

// R9 structure (RPB=8, 2 blocks/CU, dup-read tile, 1 barrier/step) with the
// gate pipes rebalanced: i,o gates via trans-sigmoid straight from index
// space (pure VALU, exact affine un-map -> no NN error on i,o), f,g via NN
// LUT gather (shared LDS pipe carried a ~1400cyc/step gather burst; now
// halved). f,g gathers issued before the i/o trans chain so gather latency
// hides under trans VALU work.
__global__ __launch_bounds__(256, 2)
void lstm2_kernel(const float* __restrict__ x,     // [4096][256]
                  const float* __restrict__ Wih0,  // [256][1]
                  const float* __restrict__ Whh0,  // [256][64]
                  const float* __restrict__ bih0,
                  const float* __restrict__ bhh0,
                  const float* __restrict__ Wih1,  // [256][64]
                  const float* __restrict__ Whh1,  // [256][64]
                  const float* __restrict__ bih1,
                  const float* __restrict__ bhh1,
                  const float* __restrict__ Wlin,  // [64][64]
                  const float* __restrict__ blin,
                  float* __restrict__ out)         // [4096][64]
{
    __shared__ float xl[TT][RPB];                      // 8 KB
    __shared__ __align__(16) _Float16 hs[2][RPB][KST]; // 4.25 KB (no dup rows)
    __shared__ float hbF[RPB][HH];                     // 2 KB
    __shared__ float lut[8192];                        // 32 KB sigma table

    const int tid  = threadIdx.x;
    const int w    = tid >> 6;
    const int l15  = tid & 15;
    const int l7   = tid & 7;          // A-frag row (dup-read: rows 8-15 -> 0-7)
    const int q    = (tid & 63) >> 4;
    const int row0 = (int)blockIdx.x * RPB;
    const int jj   = w * 16 + l15;
    const bool isA = (q < 2);          // q<2: layer-0 lanes; q>=2: layer-1 lanes
    const int  mr  = (q & 1) * 4;      // my pointwise row base (0 or 4)

    for (int idx = tid; idx < RPB * TT; idx += 256) {
        int m = idx & 7, t = idx >> 3;
        xl[t][m] = x[(row0 + m) * TT + t];
    }
    for (int idx = tid; idx < 2 * RPB * KST; idx += 256)
        ((_Float16*)hs)[idx] = (_Float16)0.f;
    for (int i = tid; i < 8192; i += 256)
        lut[i] = 1.0f / (1.0f + __expf(-(i - 4096) * (1.0f / 256.0f)));

    // sigma via nearest-neighbor LUT; f is a pre-scaled index (z*256+4096.5)
    auto lutv = [&](float f) -> float {
        f = __builtin_amdgcn_fmed3f(f, 0.0f, 8191.0f);
        return lut[(int)f];
    };
    // sigma via trans from index space (pure VALU, exact affine un-map)
    auto sig_trans = [&](float y) -> float {
        return __builtin_amdgcn_rcpf(1.f + __builtin_exp2f(fmaf(y, YK, YB)));
    };
    // tanh(c) via hardware exp2+rcp (near-exact, no gather)
    auto tanhf_fast = [&](float c) -> float {
        return fmaf(2.f, __builtin_amdgcn_rcpf(1.f + __builtin_exp2f(c * TSC2)), -1.f);
    };

    // ---- register-stationary weights, prescaled into index space ----
    float wi0s[4], b0s[4];
    v4f   b1v[4];
    v8h wh0[4][2], wi1[4][2], wh1[4][2];
    #pragma unroll
    for (int tau = 0; tau < 4; tau++) {
        float sc = (tau == 2) ? TG : SG;
        int n = tau * 64 + jj;
        wi0s[tau] = Wih0[n] * sc;
        b0s[tau]  = (bih0[n] + bhh0[n]) * sc + IOFF;
        float b1  = (bih1[n] + bhh1[n]) * sc + IOFF;
        b1v[tau]  = (v4f){b1, b1, b1, b1};
        #pragma unroll
        for (int kk = 0; kk < 2; kk++) {
            int k0 = kk * 32 + q * 8;   // B-frag: B[k0..k0+7][n=lane&15]
            v8h a, b, c;
            #pragma unroll
            for (int j = 0; j < 8; j++) {
                a[j] = (_Float16)(Whh0[n * HH + k0 + j] * sc);
                b[j] = (_Float16)(Wih1[n * HH + k0 + j] * sc);
                c[j] = (_Float16)(Whh1[n * HH + k0 + j] * sc);
            }
            wh0[tau][kk] = a; wi1[tau][kk] = b; wh1[tau][kk] = c;
        }
    }

    float cs[4] = {0.f, 0.f, 0.f, 0.f};  // c-state of MY layer, rows mr..mr+3
    __syncthreads();

    // ---- prologue t=0: ha(0) from x(0) only (written by q<2 lanes) ----
    if (isA) {
        #pragma unroll
        for (int r = 0; r < 4; r++) {
            int m = mr + r;
            float xv = xl[0][m];
            float iv = sig_trans(fmaf(xv, wi0s[0], b0s[0]));
            float gv = fmaf(2.f, lutv(fmaf(xv, wi0s[2], b0s[2])), -1.f);
            float ov = sig_trans(fmaf(xv, wi0s[3], b0s[3]));
            cs[r] = iv * gv;
            hs[0][m][jj] = (_Float16)(ov * tanhf_fast(cs[r]));
        }
    }
    __syncthreads();

    // step k: reads buf[p] {ha(k-1), hb(k-2)}, writes buf[pw] {ha(k), hb(k-1)}
    auto step = [&](int k, int p, int pw, bool last) {
        v8h a0 = *(const v8h*)&hs[p][l7][q * 8];          // ha k 0-31
        v8h a1 = *(const v8h*)&hs[p][l7][32 + q * 8];     // ha k 32-63
        v8h b0 = *(const v8h*)&hs[p][l7][64 + q * 8];     // hb k 0-31
        v8h b1 = *(const v8h*)&hs[p][l7][96 + q * 8];     // hb k 32-63
        int kx = (k < TT) ? k : (TT - 1);                 // k=256: junk x, unused
        v4f xv = *(const v4f*)&xl[kx][mr];

        v4f acc0[4], acc1[4];
        #pragma unroll
        for (int tau = 0; tau < 4; tau++) {
            #pragma unroll
            for (int r = 0; r < 4; r++) acc0[tau][r] = fmaf(xv[r], wi0s[tau], b0s[tau]);
            acc1[tau] = MFMA16(a0, wi1[tau][0], b1v[tau]);  // bias as C operand
        }
        #pragma unroll
        for (int tau = 0; tau < 4; tau++) {
            acc0[tau] = MFMA16(a0, wh0[tau][0], acc0[tau]);
            acc0[tau] = MFMA16(a1, wh0[tau][1], acc0[tau]);
            acc1[tau] = MFMA16(a1, wi1[tau][1], acc1[tau]);
            acc1[tau] = MFMA16(b0, wh1[tau][0], acc1[tau]);
            acc1[tau] = MFMA16(b1, wh1[tau][1], acc1[tau]);
        }

        // my gates: q<2 -> layer0 (C rows 0-7); q>=2 -> layer1 (C rows 8-15)
        v4f g0 = isA ? acc0[0] : acc1[0];
        v4f g1 = isA ? acc0[1] : acc1[1];
        v4f g2 = isA ? acc0[2] : acc1[2];
        v4f g3 = isA ? acc0[3] : acc1[3];

        // stage 1: f,g gathers issued first (8 loads in flight)...
        float svf[4], svg[4];
        #pragma unroll
        for (int r = 0; r < 4; r++) {
            svf[r] = lutv(g1[r]);
            svg[r] = lutv(g2[r]);
        }
        // ...i,o trans-sigmoids execute while gathers are in flight
        float svi[4], svo[4];
        #pragma unroll
        for (int r = 0; r < 4; r++) {
            svi[r] = sig_trans(g0[r]);
            svo[r] = sig_trans(g3[r]);
        }

        _Float16* wp = &hs[pw][mr][isA ? jj : (64 + jj)];

        // stage 2: c update, trans tanh, h write
        #pragma unroll
        for (int r = 0; r < 4; r++) {
            float gv = fmaf(2.f, svg[r], -1.f);
            cs[r] = fmaf(svf[r], cs[r], svi[r] * gv);
            float hv = svo[r] * tanhf_fast(cs[r]);
            wp[r * KST] = (_Float16)hv;
            if (last && !isA) hbF[mr + r][jj] = hv;
        }
        __syncthreads();
    };

    // k = 1..256 (k=256 = layer-1-only epilogue; its ha output junk-but-finite)
    for (int k = 1; k <= TT; k += 2) {
        step(k,     0, 1, false);
        step(k + 1, 1, 0, (k + 1) == TT);
    }

    // ---- out[m][n] = hbF[m][:] . Wlin[n][:] + blin[n] ----
    int m  = tid >> 5;            // 0..7
    int n0 = (tid & 31) * 2;
    float a0o = blin[n0], a1o = blin[n0 + 1];
    #pragma unroll 8
    for (int j = 0; j < HH; j++) {
        float h = hbF[m][j];
        a0o = fmaf(h, Wlin[(n0 + 0) * HH + j], a0o);
        a1o = fmaf(h, Wlin[(n0 + 1) * HH + j], a1o);
    }
    out[(row0 + m) * HH + n0]     = a0o;
    out[(row0 + m) * HH + n0 + 1] = a1o;
}

extern "C" void kernel_launch(void* const* d_in, const int* in_sizes, int n_in,
                              void* d_out, int out_size, void* d_ws, size_t ws_size,
                              hipStream_t stream) {
    const float* x    = (const float*)d_in[0];
    const float* Wih0 = (const float*)d_in[1];
    const float* Whh0 = (const float*)d_in[2];
    const float* bih0 = (const float*)d_in[3];
    const float* bhh0 = (const float*)d_in[4];
    const float* Wih1 = (const float*)d_in[5];
    const float* Whh1 = (const float*)d_in[6];
    const float* bih1 = (const float*)d_in[7];
    const float* bhh1 = (const float*)d_in[8];
    const float* Wlin = (const float*)d_in[9];
    const float* blin = (const float*)d_in[10];
    // 4096 rows / 8 per block = 512 blocks = 2 independent blocks/CU
    lstm2_kernel<<<512, 256, 0, stream>>>(x, Wih0, Whh0, bih0, bhh0,
                                          Wih1, Whh1, bih1, bhh1,
                                          Wlin, blin, (float*)d_out);
}